// Round 7
// baseline (52.672 us; speedup 1.0000x reference)
//
#include <hip/hip_runtime.h>
#include <stdint.h>

#define OUT_F 8192
#define IN_F  8192
#define NGRP  1048576      // OUT*IN/GS
#define BATCH 64
#define KS    4
#define NSTEP ((IN_F / KS) / 128)   // 16

typedef float f32x4 __attribute__((ext_vector_type(4)));
typedef _Float16 half8_t __attribute__((ext_vector_type(8)));

static __device__ __forceinline__ unsigned int pk_fma_f16(unsigned int a, unsigned int b, unsigned int c) {
  unsigned int d;
  asm("v_pk_fma_f16 %0, %1, %2, %3" : "=v"(d) : "v"(a), "v"(b), "v"(c));
  return d;
}
static __device__ __forceinline__ unsigned int pk16(float a, float b) {
  unsigned short ua = __builtin_bit_cast(unsigned short, (_Float16)a);
  unsigned short ub = __builtin_bit_cast(unsigned short, (_Float16)b);
  return (unsigned int)ua | ((unsigned int)ub << 16);
}

// ---- fused pre-pass: x fp32->f16  +  per-2-group {f16x2(s), f16x2(-(64+z)s)} ----
__global__ __launch_bounds__(256) void pre_kernel(const float* __restrict__ x, ushort* __restrict__ xh,
                                                  const float* __restrict__ scale, const float* __restrict__ zero,
                                                  uint32_t* __restrict__ szb) {
  const int b = blockIdx.x;
  if (b < 512) {                      // 512*256 = 131072 = BATCH*IN_F/4
    const int i = b * 256 + threadIdx.x;
    float4 v = ((const float4*)x)[i];
    ushort4 o;
    o.x = __builtin_bit_cast(unsigned short, (_Float16)v.x);
    o.y = __builtin_bit_cast(unsigned short, (_Float16)v.y);
    o.z = __builtin_bit_cast(unsigned short, (_Float16)v.z);
    o.w = __builtin_bit_cast(unsigned short, (_Float16)v.w);
    ((ushort4*)xh)[i] = o;
  } else {                            // 1024*256 = 262144 = NGRP/4
    const int i = (b - 512) * 256 + threadIdx.x;
    float4 s = ((const float4*)scale)[i];
    float4 z = ((const float4*)zero)[i];
    uint4 o;
    o.x = pk16(s.x, s.y);
    o.y = pk16(-(64.f + z.x) * s.x, -(64.f + z.y) * s.y);
    o.z = pk16(s.z, s.w);
    o.w = pk16(-(64.f + z.z) * s.z, -(64.f + z.w) * s.w);
    ((uint4*)szb)[i] = o;
  }
}

// ---- main fused dequant + GEMM ----
// grid 1024: ks = bid&3 (2048 k each), gq = (bid>>2)&1 (16 Wq rows), c = bid>>3.
// A (x) : registers, direct global half8 loads (L2-resident), depth-2 prefetch.
// B (W) : [32][128] f16 LDS, dequant-fused reg->LDS staging, double-buffered,
//         depth-3 W/sz register prefetch, one raw lgkm barrier per step.
__global__ __launch_bounds__(256, 4) void hqq_gemm_kernel(
    const int* __restrict__ Wq, const uint32_t* __restrict__ szb,
    const ushort* __restrict__ xh, float* __restrict__ part)
{
  __shared__ ushort blds[2][32 * 128];   // 8 KB each

  const int t    = threadIdx.x;
  const int bid  = blockIdx.x;
  const int ks   = bid & 3;
  const int gq   = (bid >> 2) & 1;
  const int c    = bid >> 3;
  const int lane = t & 63;
  const int wid  = t >> 6;
  const int kbase = ks * (IN_F / KS);

  // B staging ids: 16 Wq rows x 16 k-octets
  const int sr  = t >> 4;   // 0..15
  const int skq = t & 15;   // 0..15
  const int* __restrict__ wqp =
      Wq + (size_t)(gq * 16 + sr) * NGRP + (size_t)c * IN_F + kbase + skq * 8;
  const uint8_t* __restrict__ szp =
      (const uint8_t*)szb + ((size_t)c * IN_F + kbase + skq * 8) * 4;
  const int wbyte = (skq * 16) ^ ((sr & 7) << 4);

  // frag ids
  const int tr    = lane & 15;
  const int koff8 = (lane >> 4) * 8;
  const int am    = wid * 16 + tr;
  const ushort* __restrict__ xrow = xh + (size_t)am * IN_F + kbase + koff8;

  f32x4 acc_h = {0.f, 0.f, 0.f, 0.f};
  f32x4 acc_l = {0.f, 0.f, 0.f, 0.f};

  // W/sz register sets (depth 3), A register sets (depth 2) — all static under
  // full unroll (rule: no runtime-indexed reg arrays).
  int4  wa[3], wb[3];
  uint4 sa[3], sb[3];
  half8_t areg[2][4];

  #define LDW(set, s)                                                \
    do {                                                             \
      wa[set] = *(const int4*)(wqp + (size_t)(s) * 128);             \
      wb[set] = *(const int4*)(wqp + (size_t)(s) * 128 + 4);         \
      sa[set] = *(const uint4*)(szp + (size_t)(s) * 512);            \
      sb[set] = *(const uint4*)(szp + (size_t)(s) * 512 + 16);       \
    } while (0)
  #define LDA(set, s)                                                \
    do {                                                             \
      _Pragma("unroll")                                              \
      for (int kk = 0; kk < 4; ++kk)                                 \
        areg[set][kk] = *(const half8_t*)(xrow + (s) * 128 + kk * 32); \
    } while (0)

  // f16 magic: 0x5400 | (v<<4) == 64+v  (nibble at mantissa bits [7:4])
  auto stage_b = [&](int bi, const int4& Wa, const int4& Wb, const uint4& Sa, const uint4& Sb) {
    uint8_t* bb = (uint8_t*)&blds[bi][0];
    uint4 hi4, lo4;
    {
      unsigned tt = ((unsigned)Wa.y << 16) | (unsigned)Wa.x;
      hi4.x = pk_fma_f16((tt & 0x00F000F0u) | 0x54005400u, Sa.x, Sa.y);
      lo4.x = pk_fma_f16(((tt << 4) & 0x00F000F0u) | 0x54005400u, Sa.x, Sa.y);
    }
    {
      unsigned tt = ((unsigned)Wa.w << 16) | (unsigned)Wa.z;
      hi4.y = pk_fma_f16((tt & 0x00F000F0u) | 0x54005400u, Sa.z, Sa.w);
      lo4.y = pk_fma_f16(((tt << 4) & 0x00F000F0u) | 0x54005400u, Sa.z, Sa.w);
    }
    {
      unsigned tt = ((unsigned)Wb.y << 16) | (unsigned)Wb.x;
      hi4.z = pk_fma_f16((tt & 0x00F000F0u) | 0x54005400u, Sb.x, Sb.y);
      lo4.z = pk_fma_f16(((tt << 4) & 0x00F000F0u) | 0x54005400u, Sb.x, Sb.y);
    }
    {
      unsigned tt = ((unsigned)Wb.w << 16) | (unsigned)Wb.z;
      hi4.w = pk_fma_f16((tt & 0x00F000F0u) | 0x54005400u, Sb.z, Sb.w);
      lo4.w = pk_fma_f16(((tt << 4) & 0x00F000F0u) | 0x54005400u, Sb.z, Sb.w);
    }
    *(uint4*)(bb + sr * 256 + wbyte)        = hi4;
    *(uint4*)(bb + (sr + 16) * 256 + wbyte) = lo4;
  };

  // ---- prologue: W(0..2), A(0..1) in flight; stage B(0) ----
  LDW(0, 0);
  LDW(1, 1);
  LDW(2, 2);
  LDA(0, 0);
  LDA(1, 1);
  stage_b(0, wa[0], wb[0], sa[0], sb[0]);   // compiler waits W(0) regs
  asm volatile("s_waitcnt lgkmcnt(0)" ::: "memory");
  __builtin_amdgcn_s_barrier();

  #pragma unroll
  for (int s = 0; s < NSTEP; ++s) {
    // compute(s): A regs x blds[s&1] (compiler-counted lgkm waits)
    const uint8_t* bb = (const uint8_t*)&blds[s & 1][0];
    #pragma unroll
    for (int kk = 0; kk < 4; ++kk) {
      const int colb = (koff8 + kk * 32) * 2;
      half8_t a   = areg[s & 1][kk];
      half8_t bhi = *(const half8_t*)(bb + tr * 256 + (colb ^ ((tr & 7) << 4)));
      half8_t blo = *(const half8_t*)(bb + (tr + 16) * 256 + (colb ^ ((tr & 7) << 4)));
      acc_h = __builtin_amdgcn_mfma_f32_16x16x32_f16(a, bhi, acc_h, 0, 0, 0);
      acc_l = __builtin_amdgcn_mfma_f32_16x16x32_f16(a, blo, acc_l, 0, 0, 0);
    }

    // dequant + ds_write B(s+1) from W set (s+1)%3 (loaded 2-3 iters ago)
    if (s + 1 < NSTEP)
      stage_b((s + 1) & 1, wa[(s + 1) % 3], wb[(s + 1) % 3], sa[(s + 1) % 3], sb[(s + 1) % 3]);

    // refill: A(s+2) into A set s&1 (just consumed), W(s+3) into W set s%3 (consumed @ s-1)
    if (s + 2 < NSTEP) LDA(s & 1, s + 2);
    if (s + 3 < NSTEP) LDW(s % 3, s + 3);

    if (s + 1 < NSTEP) {
      asm volatile("s_waitcnt lgkmcnt(0)" ::: "memory");   // B(s+1) writes done
      __builtin_amdgcn_s_barrier();                        // vmcnt NOT drained
    }
  }
  #undef LDW
  #undef LDA

  // epilogue: C/D col = lane&15 -> o, row = (lane>>4)*4 + j -> m
  const int o_hi = (gq * 16 + tr) * 128 + c;
  const int m0   = wid * 16 + (lane >> 4) * 4;
  float* p_hi = part + ((size_t)ks * OUT_F + o_hi) * BATCH + m0;
  float* p_lo = part + ((size_t)ks * OUT_F + o_hi + 4096) * BATCH + m0;
  *(float4*)p_hi = (float4){acc_h[0], acc_h[1], acc_h[2], acc_h[3]};
  *(float4*)p_lo = (float4){acc_l[0], acc_l[1], acc_l[2], acc_l[3]};
}

// ---- split-K reduce + bias + transpose to out[m][o] ----
__global__ __launch_bounds__(256) void reduce_kernel(const float* __restrict__ part,
                                                     const float* __restrict__ bias,
                                                     float* __restrict__ out)
{
  __shared__ float tile[32][65];
  const int ob = blockIdx.x;          // o-range [ob*32, +32)
  const int t  = threadIdx.x;
  {
    const int ol = t >> 3;            // 0..31
    const int mg = t & 7;             // m-octet
    const int o  = ob * 32 + ol;
    const size_t base = (size_t)o * BATCH + mg * 8;
    float s[8] = {0, 0, 0, 0, 0, 0, 0, 0};
    #pragma unroll
    for (int ks = 0; ks < KS; ++ks) {
      const float* p = part + (size_t)ks * OUT_F * BATCH + base;
      float4 a = *(const float4*)p;
      float4 b = *(const float4*)(p + 4);
      s[0] += a.x; s[1] += a.y; s[2] += a.z; s[3] += a.w;
      s[4] += b.x; s[5] += b.y; s[6] += b.z; s[7] += b.w;
    }
    const float bv = bias[o];
    #pragma unroll
    for (int j = 0; j < 8; ++j) tile[ol][mg * 8 + j] = s[j] + bv;
  }
  __syncthreads();
  {
    const int m  = t >> 2;            // 0..63
    const int og = (t & 3) * 8;       // 0..31
    float r[8];
    #pragma unroll
    for (int j = 0; j < 8; ++j) r[j] = tile[og + j][m];
    float* op = out + (size_t)m * OUT_F + ob * 32 + og;
    *(float4*)op       = (float4){r[0], r[1], r[2], r[3]};
    *(float4*)(op + 4) = (float4){r[4], r[5], r[6], r[7]};
  }
}

// ---- correctness fallback (tiny ws), fp32 ----
__global__ void hqq_fallback_kernel(const float* __restrict__ x, const int* __restrict__ Wq,
                                    const float* __restrict__ scale, const float* __restrict__ zero,
                                    const float* __restrict__ bias, float* __restrict__ out)
{
  int idx = blockIdx.x * blockDim.x + threadIdx.x;
  int b = idx >> 13;
  int o = idx & 8191;
  int g = o >> 7, cc = o & 127;
  int r = g & 31;
  bool hi = (g < 32);
  const int*   wrow = Wq    + (size_t)r  * NGRP + (size_t)cc * IN_F;
  const float* srow = scale + (size_t)cc * IN_F;
  const float* zrow = zero  + (size_t)cc * IN_F;
  const float* xrow = x     + (size_t)b  * IN_F;
  float acc = 0.f;
  for (int k = 0; k < IN_F; ++k) {
    int v = wrow[k];
    float nib = (float)(hi ? (v >> 4) : (v & 15));
    acc += xrow[k] * ((nib - zrow[k]) * srow[k]);
  }
  out[idx] = acc + bias[o];
}

extern "C" void kernel_launch(void* const* d_in, const int* in_sizes, int n_in,
                              void* d_out, int out_size, void* d_ws, size_t ws_size,
                              hipStream_t stream) {
  const float* x     = (const float*)d_in[0];
  const int*   Wq    = (const int*)d_in[1];
  const float* scale = (const float*)d_in[2];
  const float* zero  = (const float*)d_in[3];
  const float* bias  = (const float*)d_in[4];
  float* out = (float*)d_out;

  const size_t xh_bytes   = (size_t)BATCH * IN_F * sizeof(ushort);        // 1 MB
  const size_t sz_bytes   = (size_t)NGRP * 4;                             // 4 MB
  const size_t part_bytes = (size_t)KS * BATCH * OUT_F * sizeof(float);   // 8 MB

  if (ws_size >= xh_bytes + sz_bytes + part_bytes) {
    ushort*   xh   = (ushort*)d_ws;
    uint32_t* szb  = (uint32_t*)((char*)d_ws + xh_bytes);
    float*    part = (float*)((char*)d_ws + xh_bytes + sz_bytes);
    pre_kernel<<<1536, 256, 0, stream>>>(x, xh, scale, zero, szb);
    hqq_gemm_kernel<<<128 * 2 * KS, 256, 0, stream>>>(Wq, szb, xh, part);
    reduce_kernel<<<OUT_F / 32, 256, 0, stream>>>(part, bias, out);
  } else {
    hqq_fallback_kernel<<<(BATCH * OUT_F) / 256, 256, 0, stream>>>(x, Wq, scale, zero, bias, out);
  }
}